// Round 1
// baseline (2558.826 us; speedup 1.0000x reference)
//
#include <hip/hip_runtime.h>

// SparseFinerAttention on MI355X — round 0 (correctness-first, fp16 pipeline)
// B=2 N=4096 C=768 H=12 D=64 SCALE=1/8 K_keep=409
//
// Pipeline: cast->fp16; Q/K/V NT-GEMMs (MFMA 16x16x32_f16); fused attention
// (QK^T -> exact top-k on quantized logits -> masked dense PV); out GEMM+bias.

typedef unsigned short u16;
typedef unsigned int   u32;
typedef float    f32x4 __attribute__((ext_vector_type(4)));
typedef _Float16 f16x8 __attribute__((ext_vector_type(8)));
typedef u16      u16x8 __attribute__((ext_vector_type(8)));
typedef u16      u16x4 __attribute__((ext_vector_type(4)));

#define NHEADS 12
#define SEQ    4096
#define DIMC   768
#define HDIM   64
#define KKEEP  409

__device__ __forceinline__ f32x4 mfma16(f16x8 a, f16x8 b, f32x4 c) {
  return __builtin_amdgcn_mfma_f32_16x16x32_f16(a, b, c, 0, 0, 0);
}
__device__ __forceinline__ u16 f2h_bits(float f) {
  return __builtin_bit_cast(u16, (_Float16)f);
}
__device__ __forceinline__ float h2f_bits(u16 b) {
  return (float)__builtin_bit_cast(_Float16, b);
}

// ---------------- cast fp32 -> fp16 (vectorized) ----------------
__global__ __launch_bounds__(256) void cast_f32_to_f16(const float* __restrict__ in,
                                                       u16* __restrict__ out, int n4) {
  int i = blockIdx.x * 256 + threadIdx.x;
  if (i >= n4) return;
  float4 v = ((const float4*)in)[i];
  u16x4 o;
  o[0] = f2h_bits(v.x); o[1] = f2h_bits(v.y); o[2] = f2h_bits(v.z); o[3] = f2h_bits(v.w);
  ((u16x4*)out)[i] = o;
}

// ---------------- NT GEMM: C[M][768] = A[M][768] @ B[768][768]^T ----------------
// MODE 0: store fp16, head layout dst[b][h][n][d], value*scale   (Q with scale=0.125, K scale=1)
// MODE 1: store fp16, transposed head layout dst[b][h][d][n]     (V)
// MODE 2: store fp32 + bias, flat [M][768]                       (final projection)
template<int MODE>
__global__ __launch_bounds__(256) void gemm_nt(const u16* __restrict__ A, const u16* __restrict__ B,
                                               float scale, const float* __restrict__ bias,
                                               void* __restrict__ dstv) {
  __shared__ __align__(16) u16 As[128 * 64];
  __shared__ __align__(16) u16 Bs[128 * 64];
  const int tid  = threadIdx.x;
  const int lane = tid & 63, wave = tid >> 6;
  const int l15 = lane & 15, l4 = lane >> 4;
  const int row0 = blockIdx.x * 128, col0 = blockIdx.y * 128;
  const int wr = (wave >> 1) * 64, wc = (wave & 1) * 64;
  f32x4 acc[4][4];
#pragma unroll
  for (int i = 0; i < 4; i++)
#pragma unroll
    for (int j = 0; j < 4; j++) acc[i][j] = f32x4{0.f, 0.f, 0.f, 0.f};

  for (int k0 = 0; k0 < DIMC; k0 += 64) {
#pragma unroll
    for (int i = 0; i < 4; i++) {
      int id = tid + i * 256;
      int r = id >> 3, c = id & 7;
      f16x8 va = *(const f16x8*)(A + (size_t)(row0 + r) * DIMC + k0 + c * 8);
      f16x8 vb = *(const f16x8*)(B + (size_t)(col0 + r) * DIMC + k0 + c * 8);
      *(f16x8*)(As + r * 64 + ((c ^ (r & 7)) << 3)) = va;
      *(f16x8*)(Bs + r * 64 + ((c ^ (r & 7)) << 3)) = vb;
    }
    __syncthreads();
#pragma unroll
    for (int ks = 0; ks < 2; ++ks) {
      f16x8 af[4], bfr[4];
#pragma unroll
      for (int i = 0; i < 4; i++) {
        int r = wr + i * 16 + l15;
        int c = ks * 4 + l4;
        af[i] = *(const f16x8*)(As + r * 64 + ((c ^ (r & 7)) << 3));
        int r2 = wc + i * 16 + l15;
        bfr[i] = *(const f16x8*)(Bs + r2 * 64 + ((c ^ (r2 & 7)) << 3));
      }
#pragma unroll
      for (int i = 0; i < 4; i++)
#pragma unroll
        for (int j = 0; j < 4; j++) acc[i][j] = mfma16(af[i], bfr[j], acc[i][j]);
    }
    __syncthreads();
  }

  // epilogue: C/D layout col=lane&15, row=(lane>>4)*4+jj  [m89-verified]
#pragma unroll
  for (int i = 0; i < 4; i++) {
#pragma unroll
    for (int j = 0; j < 4; j++) {
      int rowb = row0 + wr + i * 16 + (l4 << 2);
      int col  = col0 + wc + j * 16 + l15;
      if (MODE == 2) {
        float* dst = (float*)dstv;
        float bv = bias[col];
#pragma unroll
        for (int jj = 0; jj < 4; jj++)
          dst[(size_t)(rowb + jj) * DIMC + col] = acc[i][j][jj] + bv;
      } else if (MODE == 0) {
        u16* dst = (u16*)dstv;
        int hh = col >> 6, d = col & 63;
#pragma unroll
        for (int jj = 0; jj < 4; jj++) {
          int row = rowb + jj;
          int bb = row >> 12, n = row & 4095;
          dst[(((size_t)bb * NHEADS + hh) * SEQ + n) * HDIM + d] = f2h_bits(acc[i][j][jj] * scale);
        }
      } else { // MODE 1: V transposed [b][h][d][n]
        u16* dst = (u16*)dstv;
        int hh = col >> 6, d = col & 63;
        int bb = rowb >> 12, nb = rowb & 4095;
        u16x4 pack;
#pragma unroll
        for (int jj = 0; jj < 4; jj++) pack[jj] = f2h_bits(acc[i][j][jj] * scale);
        *(u16x4*)(dst + (((size_t)bb * NHEADS + hh) * HDIM + d) * SEQ + nb) = pack;
      }
    }
  }
}

// ---------------- fused attention: QK^T -> softmax + exact top-k -> masked PV ----------------
// 1 workgroup per (b, h, 16-row q block); 4 waves split the 4096-key range.
// S: [16][4096] fp16 logits in LDS, XOR-swizzled:
//   sidx(q,m) = q*4096 + (((m>>3) ^ (q&7))<<3 | (m&7))
__global__ __launch_bounds__(256) void attn_kernel(const u16* __restrict__ Q, const u16* __restrict__ Kb,
                                                   const u16* __restrict__ Vt, u16* __restrict__ Ob) {
  __shared__ __align__(16) u16 S[16 * 4096];      // 128 KB
  __shared__ float Opart[4][16][64];              // 16 KB
  const int tid  = threadIdx.x;
  const int lane = tid & 63, wave = tid >> 6;
  const int l15 = lane & 15, l4 = lane >> 4;
  const int h = blockIdx.y, b = blockIdx.z;
  const int bh = b * NHEADS + h;
  const int q0 = blockIdx.x * 16;
  const u16* Qh = Q  + ((size_t)bh * SEQ + q0) * HDIM;
  const u16* Kh = Kb + (size_t)bh * SEQ * HDIM;
  const u16* Vh = Vt + (size_t)bh * HDIM * SEQ;

  // Q fragments (rows q0..q0+15), Q already pre-scaled by 1/8
  f16x8 qa0 = *(const f16x8*)(Qh + l15 * HDIM + l4 * 8);
  f16x8 qa1 = *(const f16x8*)(Qh + l15 * HDIM + 32 + l4 * 8);

  // ---- QK^T: wave w covers keys [w*1024, (w+1)*1024) ----
  for (int t = 0; t < 64; ++t) {
    int m0 = wave * 1024 + t * 16;
    const u16* kp = Kh + (size_t)(m0 + l15) * HDIM + l4 * 8;
    f16x8 kb0 = *(const f16x8*)kp;
    f16x8 kb1 = *(const f16x8*)(kp + 32);
    f32x4 acc = f32x4{0.f, 0.f, 0.f, 0.f};
    acc = mfma16(qa0, kb0, acc);
    acc = mfma16(qa1, kb1, acc);
    int col = m0 + l15;
#pragma unroll
    for (int j = 0; j < 4; j++) {
      int row = l4 * 4 + j;
      S[(row << 12) + ((((col >> 3) ^ (row & 7))) << 3) + (col & 7)] = f2h_bits(acc[j]);
    }
  }
  __syncthreads();

  // ---- per-row softmax denom + exact top-k(409) threshold; wave w owns rows 4w..4w+3 ----
  for (int rr = 0; rr < 4; ++rr) {
    const int row = wave * 4 + rr;
    const u32 rbase = (u32)row << 12;
    const u32 rx = (u32)(row & 7) << 3;
    // register-cache the row as order-preserving u16 keys; lane owns chunks c = cc*64+lane
    u32 key[8][8];
#pragma unroll
    for (int cc = 0; cc < 8; ++cc) {
      u32 c = (u32)cc * 64 + lane;
      u16x8 v = *(const u16x8*)(S + rbase + ((c << 3) ^ rx));
#pragma unroll
      for (int e = 0; e < 8; e++) {
        u32 u = v[e];
        key[cc][e] = (u & 0x8000u) ? (u ^ 0xFFFFu) : (u | 0x8000u);
      }
    }
    // binary search: smallest t with count(key > t) < KKEEP  => t = Kth-largest key
    u32 lo = 0, hi = 65535;
    while (lo < hi) {
      u32 mid = (lo + hi) >> 1;
      int cnt = 0;
#pragma unroll
      for (int cc = 0; cc < 8; ++cc)
#pragma unroll
        for (int e = 0; e < 8; e++) cnt += (key[cc][e] > mid) ? 1 : 0;
#pragma unroll
      for (int o = 32; o; o >>= 1) cnt += __shfl_xor(cnt, o);
      if (cnt < KKEEP) hi = mid; else lo = mid + 1;
    }
    const u32 t = lo;
    // stats: count > t, and softmax denom Z = sum exp(l)  (logits ~O(1): no max-sub needed)
    int c1 = 0; float z = 0.f;
#pragma unroll
    for (int cc = 0; cc < 8; ++cc)
#pragma unroll
      for (int e = 0; e < 8; e++) {
        u32 k = key[cc][e];
        c1 += (k > t) ? 1 : 0;
        u16 hb = (k & 0x8000u) ? (u16)(k ^ 0x8000u) : (u16)(k ^ 0xFFFFu);
        z += __expf(h2f_bits(hb));
      }
#pragma unroll
    for (int o = 32; o; o >>= 1) { c1 += __shfl_xor(c1, o); z += __shfl_xor(z, o); }
    const float invZ = 1.f / z;
    const int r = KKEEP - c1;   // how many ==t entries to keep (lowest index first)
    // rank of ==t entries in m-order: m = (cc*64+lane)*8 + e -> lexicographic (cc, lane, e)
    int lanepre[8], eqtot[8];
#pragma unroll
    for (int cc = 0; cc < 8; ++cc) {
      int ec = 0;
#pragma unroll
      for (int e = 0; e < 8; e++) ec += (key[cc][e] == t) ? 1 : 0;
      int inc = ec;
#pragma unroll
      for (int o = 1; o < 64; o <<= 1) { int p = __shfl_up(inc, o); if (lane >= o) inc += p; }
      lanepre[cc] = inc - ec;
      eqtot[cc]   = __shfl(inc, 63);
    }
    int run = 0, rank0[8];
#pragma unroll
    for (int cc = 0; cc < 8; ++cc) { rank0[cc] = run + lanepre[cc]; run += eqtot[cc]; }
    // write back masked softmax weights (fp16) in place
#pragma unroll
    for (int cc = 0; cc < 8; ++cc) {
      int rk = rank0[cc];
      u16x8 wv;
#pragma unroll
      for (int e = 0; e < 8; e++) {
        u32 k = key[cc][e];
        bool keep;
        if (k > t) keep = true;
        else if (k == t) { keep = (rk < r); rk++; }
        else keep = false;
        float w = 0.f;
        if (keep) {
          u16 hb = (k & 0x8000u) ? (u16)(k ^ 0x8000u) : (u16)(k ^ 0xFFFFu);
          w = __expf(h2f_bits(hb)) * invZ;
        }
        wv[e] = f2h_bits(w);
      }
      u32 c = (u32)cc * 64 + lane;
      *(u16x8*)(S + rbase + ((c << 3) ^ rx)) = wv;
    }
  }
  __syncthreads();

  // ---- masked dense PV: O[16][64] += P[16][m-range] @ V^T; wave w covers its 1024 keys ----
  f32x4 oacc[4];
#pragma unroll
  for (int dt = 0; dt < 4; dt++) oacc[dt] = f32x4{0.f, 0.f, 0.f, 0.f};
  for (int ks = 0; ks < 32; ++ks) {
    int mb = wave * 1024 + ks * 32;
    u32 c = (u32)(mb >> 3) + l4;
    f16x8 pa = *(const f16x8*)(S + (l15 << 12) + (((c ^ (l15 & 7))) << 3));
#pragma unroll
    for (int dt = 0; dt < 4; ++dt) {
      const u16* vp = Vh + (size_t)(dt * 16 + l15) * SEQ + mb + l4 * 8;
      f16x8 vb = *(const f16x8*)vp;
      oacc[dt] = mfma16(pa, vb, oacc[dt]);
    }
  }
#pragma unroll
  for (int dt = 0; dt < 4; dt++)
#pragma unroll
    for (int j = 0; j < 4; j++)
      Opart[wave][l4 * 4 + j][dt * 16 + l15] = oacc[dt][j];
  __syncthreads();
  for (int i = tid; i < 16 * 64; i += 256) {
    int row = i >> 6, d = i & 63;
    float v = Opart[0][row][d] + Opart[1][row][d] + Opart[2][row][d] + Opart[3][row][d];
    Ob[((size_t)b * SEQ + q0 + row) * DIMC + h * HDIM + d] = f2h_bits(v);
  }
}

// ---------------- launch ----------------
extern "C" void kernel_launch(void* const* d_in, const int* in_sizes, int n_in,
                              void* d_out, int out_size, void* d_ws, size_t ws_size,
                              hipStream_t stream) {
  const float* x  = (const float*)d_in[0];
  const float* Wq = (const float*)d_in[1];
  const float* Wk = (const float*)d_in[2];
  const float* Wv = (const float*)d_in[3];
  const float* Wp = (const float*)d_in[4];
  const float* bp = (const float*)d_in[5];
  float* out = (float*)d_out;

  const size_t M = 2 * (size_t)SEQ;            // 8192
  const size_t XB = M * DIMC * 2;              // fp16 x / Q / K / Vt / O buffers
  const size_t WB = (size_t)DIMC * DIMC * 2;

  char* w = (char*)d_ws;
  u16* xb   = (u16*)w; w += XB;
  u16* Wqb  = (u16*)w; w += WB;
  u16* Wkb  = (u16*)w; w += WB;
  u16* Wvb  = (u16*)w; w += WB;
  u16* Wpb  = (u16*)w; w += WB;
  u16* Qb   = (u16*)w; w += XB;
  u16* Kbuf = (u16*)w; w += XB;
  u16* Vtb  = (u16*)w; w += XB;
  u16* Obuf = (u16*)w; w += XB;

  cast_f32_to_f16<<<6144, 256, 0, stream>>>(x,  xb,  (int)(M * DIMC / 4));
  cast_f32_to_f16<<<576,  256, 0, stream>>>(Wq, Wqb, (int)(WB / 8));
  cast_f32_to_f16<<<576,  256, 0, stream>>>(Wk, Wkb, (int)(WB / 8));
  cast_f32_to_f16<<<576,  256, 0, stream>>>(Wv, Wvb, (int)(WB / 8));
  cast_f32_to_f16<<<576,  256, 0, stream>>>(Wp, Wpb, (int)(WB / 8));

  dim3 gg(64, 6);
  gemm_nt<0><<<gg, 256, 0, stream>>>(xb, Wqb, 0.125f, nullptr, Qb);    // Q pre-scaled
  gemm_nt<0><<<gg, 256, 0, stream>>>(xb, Wkb, 1.0f,   nullptr, Kbuf);
  gemm_nt<1><<<gg, 256, 0, stream>>>(xb, Wvb, 1.0f,   nullptr, Vtb);   // V transposed

  attn_kernel<<<dim3(256, NHEADS, 2), 256, 0, stream>>>(Qb, Kbuf, Vtb, Obuf);

  gemm_nt<2><<<gg, 256, 0, stream>>>(Obuf, Wpb, 1.0f, bp, out);
}

// Round 2
// 1962.061 us; speedup vs baseline: 1.3042x; 1.3042x over previous
//
#include <hip/hip_runtime.h>

// SparseFinerAttention on MI355X — round 2 (occupancy: 16 waves/block, LDS alias)
// B=2 N=4096 C=768 H=12 D=64 SCALE=1/8 K_keep=409
//
// Pipeline: cast->fp16; Q/K/V NT-GEMMs (MFMA 16x16x32_f16); fused attention
// (QK^T -> exact top-k on quantized logits -> masked dense PV); out GEMM+bias.

typedef unsigned short u16;
typedef unsigned int   u32;
typedef float    f32x4 __attribute__((ext_vector_type(4)));
typedef _Float16 f16x8 __attribute__((ext_vector_type(8)));
typedef u16      u16x8 __attribute__((ext_vector_type(8)));
typedef u16      u16x4 __attribute__((ext_vector_type(4)));

#define NHEADS 12
#define SEQ    4096
#define DIMC   768
#define HDIM   64
#define KKEEP  409

__device__ __forceinline__ f32x4 mfma16(f16x8 a, f16x8 b, f32x4 c) {
  return __builtin_amdgcn_mfma_f32_16x16x32_f16(a, b, c, 0, 0, 0);
}
__device__ __forceinline__ u16 f2h_bits(float f) {
  return __builtin_bit_cast(u16, (_Float16)f);
}
__device__ __forceinline__ float h2f_bits(u16 b) {
  return (float)__builtin_bit_cast(_Float16, b);
}

// ---------------- cast fp32 -> fp16 (vectorized) ----------------
__global__ __launch_bounds__(256) void cast_f32_to_f16(const float* __restrict__ in,
                                                       u16* __restrict__ out, int n4) {
  int i = blockIdx.x * 256 + threadIdx.x;
  if (i >= n4) return;
  float4 v = ((const float4*)in)[i];
  u16x4 o;
  o[0] = f2h_bits(v.x); o[1] = f2h_bits(v.y); o[2] = f2h_bits(v.z); o[3] = f2h_bits(v.w);
  ((u16x4*)out)[i] = o;
}

// ---------------- NT GEMM: C[M][768] = A[M][768] @ B[768][768]^T ----------------
// MODE 0: store fp16, head layout dst[b][h][n][d], value*scale   (Q with scale=0.125, K scale=1)
// MODE 1: store fp16, transposed head layout dst[b][h][d][n]     (V)
// MODE 2: store fp32 + bias, flat [M][768]                       (final projection)
template<int MODE>
__global__ __launch_bounds__(256) void gemm_nt(const u16* __restrict__ A, const u16* __restrict__ B,
                                               float scale, const float* __restrict__ bias,
                                               void* __restrict__ dstv) {
  __shared__ __align__(16) u16 As[128 * 64];
  __shared__ __align__(16) u16 Bs[128 * 64];
  const int tid  = threadIdx.x;
  const int lane = tid & 63, wave = tid >> 6;
  const int l15 = lane & 15, l4 = lane >> 4;
  const int row0 = blockIdx.x * 128, col0 = blockIdx.y * 128;
  const int wr = (wave >> 1) * 64, wc = (wave & 1) * 64;
  f32x4 acc[4][4];
#pragma unroll
  for (int i = 0; i < 4; i++)
#pragma unroll
    for (int j = 0; j < 4; j++) acc[i][j] = f32x4{0.f, 0.f, 0.f, 0.f};

  for (int k0 = 0; k0 < DIMC; k0 += 64) {
#pragma unroll
    for (int i = 0; i < 4; i++) {
      int id = tid + i * 256;
      int r = id >> 3, c = id & 7;
      f16x8 va = *(const f16x8*)(A + (size_t)(row0 + r) * DIMC + k0 + c * 8);
      f16x8 vb = *(const f16x8*)(B + (size_t)(col0 + r) * DIMC + k0 + c * 8);
      *(f16x8*)(As + r * 64 + ((c ^ (r & 7)) << 3)) = va;
      *(f16x8*)(Bs + r * 64 + ((c ^ (r & 7)) << 3)) = vb;
    }
    __syncthreads();
#pragma unroll
    for (int ks = 0; ks < 2; ++ks) {
      f16x8 af[4], bfr[4];
#pragma unroll
      for (int i = 0; i < 4; i++) {
        int r = wr + i * 16 + l15;
        int c = ks * 4 + l4;
        af[i] = *(const f16x8*)(As + r * 64 + ((c ^ (r & 7)) << 3));
        int r2 = wc + i * 16 + l15;
        bfr[i] = *(const f16x8*)(Bs + r2 * 64 + ((c ^ (r2 & 7)) << 3));
      }
#pragma unroll
      for (int i = 0; i < 4; i++)
#pragma unroll
        for (int j = 0; j < 4; j++) acc[i][j] = mfma16(af[i], bfr[j], acc[i][j]);
    }
    __syncthreads();
  }

  // epilogue: C/D layout col=lane&15, row=(lane>>4)*4+jj  [m89-verified]
#pragma unroll
  for (int i = 0; i < 4; i++) {
#pragma unroll
    for (int j = 0; j < 4; j++) {
      int rowb = row0 + wr + i * 16 + (l4 << 2);
      int col  = col0 + wc + j * 16 + l15;
      if (MODE == 2) {
        float* dst = (float*)dstv;
        float bv = bias[col];
#pragma unroll
        for (int jj = 0; jj < 4; jj++)
          dst[(size_t)(rowb + jj) * DIMC + col] = acc[i][j][jj] + bv;
      } else if (MODE == 0) {
        u16* dst = (u16*)dstv;
        int hh = col >> 6, d = col & 63;
#pragma unroll
        for (int jj = 0; jj < 4; jj++) {
          int row = rowb + jj;
          int bb = row >> 12, n = row & 4095;
          dst[(((size_t)bb * NHEADS + hh) * SEQ + n) * HDIM + d] = f2h_bits(acc[i][j][jj] * scale);
        }
      } else { // MODE 1: V transposed [b][h][d][n]
        u16* dst = (u16*)dstv;
        int hh = col >> 6, d = col & 63;
        int bb = rowb >> 12, nb = rowb & 4095;
        u16x4 pack;
#pragma unroll
        for (int jj = 0; jj < 4; jj++) pack[jj] = f2h_bits(acc[i][j][jj] * scale);
        *(u16x4*)(dst + (((size_t)bb * NHEADS + hh) * HDIM + d) * SEQ + nb) = pack;
      }
    }
  }
}

// ---------------- fused attention: QK^T -> softmax + exact top-k -> masked PV ----------------
// 1 workgroup (1024 thr, 16 waves) per (b, h, 16-row q block).
// QK^T:    wave w computes keys [w*256, (w+1)*256) via swapped mfma(K,Q) -> u16x4 LDS writes.
// top-k:   wave w owns row w (binary search on order-preserving u16 keys, exact ties).
// PV:      wave w covers its 256 keys; fp32 partials aliased into S after barrier.
// S: [16][4096] fp16, XOR-swizzled: sidx(q,m) = q*4096 + (((m>>3) ^ (q&7))<<3 | (m&7))
__global__ __launch_bounds__(1024) void attn_kernel(const u16* __restrict__ Q, const u16* __restrict__ Kb,
                                                    const u16* __restrict__ Vt, u16* __restrict__ Ob) {
  __shared__ __align__(16) u16 S[16 * 4096];      // 128 KB (re-used for fp32 O-partials)
  const int tid  = threadIdx.x;
  const int lane = tid & 63, wave = tid >> 6;
  const int l15 = lane & 15, l4 = lane >> 4;
  const int h = blockIdx.y, b = blockIdx.z;
  const int bh = b * NHEADS + h;
  const int q0 = blockIdx.x * 16;
  const u16* Qh = Q  + ((size_t)bh * SEQ + q0) * HDIM;
  const u16* Kh = Kb + (size_t)bh * SEQ * HDIM;
  const u16* Vh = Vt + (size_t)bh * HDIM * SEQ;

  // Q fragments (rows q0..q0+15), Q already pre-scaled by 1/8. B-operand: l15 = q row.
  f16x8 qa0 = *(const f16x8*)(Qh + l15 * HDIM + l4 * 8);
  f16x8 qa1 = *(const f16x8*)(Qh + l15 * HDIM + 32 + l4 * 8);

  // ---- QK^T (swapped): wave w covers keys [w*256, (w+1)*256) ----
  // mfma(K,Q): out row (l4*4+j) = key-within-16, col (l15) = q row.
  const int m0base = wave * 256;
#pragma unroll 2
  for (int t = 0; t < 16; ++t) {
    int m0 = m0base + t * 16;
    const u16* kp = Kh + (size_t)(m0 + l15) * HDIM + l4 * 8;
    f16x8 kb0 = *(const f16x8*)kp;
    f16x8 kb1 = *(const f16x8*)(kp + 32);
    f32x4 acc = f32x4{0.f, 0.f, 0.f, 0.f};
    acc = mfma16(kb0, qa0, acc);
    acc = mfma16(kb1, qa1, acc);
    // lane holds keys m0 + l4*4 + {0..3} of q-row l15 -> one u16x4 store
    int g = (m0 >> 3) + (l4 >> 1);            // 8-key group index
    u16x4 pack;
#pragma unroll
    for (int j = 0; j < 4; j++) pack[j] = f2h_bits(acc[j]);
    *(u16x4*)(S + (l15 << 12) + ((g ^ (l15 & 7)) << 3) + ((l4 & 1) << 2)) = pack;
  }
  __syncthreads();

  // ---- per-row softmax denom + exact top-k(409) threshold; wave w owns row w ----
  {
    const int row = wave;
    const u32 rbase = (u32)row << 12;
    const u32 rx = (u32)(row & 7) << 3;
    // register-cache the row as order-preserving u16 keys; lane owns chunks c = cc*64+lane
    u32 key[8][8];
#pragma unroll
    for (int cc = 0; cc < 8; ++cc) {
      u32 c = (u32)cc * 64 + lane;
      u16x8 v = *(const u16x8*)(S + rbase + ((c << 3) ^ rx));
#pragma unroll
      for (int e = 0; e < 8; e++) {
        u32 u = v[e];
        key[cc][e] = (u & 0x8000u) ? (u ^ 0xFFFFu) : (u | 0x8000u);
      }
    }
    // binary search: smallest t with count(key > t) < KKEEP  => t = Kth-largest key
    u32 lo = 0, hi = 65535;
    while (lo < hi) {
      u32 mid = (lo + hi) >> 1;
      int cnt = 0;
#pragma unroll
      for (int cc = 0; cc < 8; ++cc)
#pragma unroll
        for (int e = 0; e < 8; e++) cnt += (key[cc][e] > mid) ? 1 : 0;
#pragma unroll
      for (int o = 32; o; o >>= 1) cnt += __shfl_xor(cnt, o);
      if (cnt < KKEEP) hi = mid; else lo = mid + 1;
    }
    const u32 t = lo;
    // stats: count > t, and softmax denom Z = sum exp(l)  (logits ~O(1): no max-sub needed)
    int c1 = 0; float z = 0.f;
#pragma unroll
    for (int cc = 0; cc < 8; ++cc)
#pragma unroll
      for (int e = 0; e < 8; e++) {
        u32 k = key[cc][e];
        c1 += (k > t) ? 1 : 0;
        u16 hb = (k & 0x8000u) ? (u16)(k ^ 0x8000u) : (u16)(k ^ 0xFFFFu);
        z += __expf(h2f_bits(hb));
      }
#pragma unroll
    for (int o = 32; o; o >>= 1) { c1 += __shfl_xor(c1, o); z += __shfl_xor(z, o); }
    const float invZ = 1.f / z;
    const int r = KKEEP - c1;   // how many ==t entries to keep (lowest index first)
    // rank of ==t entries in m-order: m = (cc*64+lane)*8 + e -> lexicographic (cc, lane, e)
    int lanepre[8], eqtot[8];
#pragma unroll
    for (int cc = 0; cc < 8; ++cc) {
      int ec = 0;
#pragma unroll
      for (int e = 0; e < 8; e++) ec += (key[cc][e] == t) ? 1 : 0;
      int inc = ec;
#pragma unroll
      for (int o = 1; o < 64; o <<= 1) { int p = __shfl_up(inc, o); if (lane >= o) inc += p; }
      lanepre[cc] = inc - ec;
      eqtot[cc]   = __shfl(inc, 63);
    }
    int run = 0, rank0[8];
#pragma unroll
    for (int cc = 0; cc < 8; ++cc) { rank0[cc] = run + lanepre[cc]; run += eqtot[cc]; }
    // write back masked softmax weights (fp16) in place
#pragma unroll
    for (int cc = 0; cc < 8; ++cc) {
      int rk = rank0[cc];
      u16x8 wv;
#pragma unroll
      for (int e = 0; e < 8; e++) {
        u32 k = key[cc][e];
        bool keep;
        if (k > t) keep = true;
        else if (k == t) { keep = (rk < r); rk++; }
        else keep = false;
        float w = 0.f;
        if (keep) {
          u16 hb = (k & 0x8000u) ? (u16)(k ^ 0x8000u) : (u16)(k ^ 0xFFFFu);
          w = __expf(h2f_bits(hb)) * invZ;
        }
        wv[e] = f2h_bits(w);
      }
      u32 c = (u32)cc * 64 + lane;
      *(u16x8*)(S + rbase + ((c << 3) ^ rx)) = wv;
    }
  }
  __syncthreads();

  // ---- masked dense PV: O[16][64] += P[16][m-range] @ V^T; wave w covers its 256 keys ----
  f32x4 oacc[4];
#pragma unroll
  for (int dt = 0; dt < 4; dt++) oacc[dt] = f32x4{0.f, 0.f, 0.f, 0.f};
#pragma unroll 2
  for (int ks = 0; ks < 8; ++ks) {
    int mb = wave * 256 + ks * 32;
    u32 c = (u32)(mb >> 3) + l4;
    f16x8 pa = *(const f16x8*)(S + (l15 << 12) + (((c ^ (l15 & 7))) << 3));
#pragma unroll
    for (int dt = 0; dt < 4; ++dt) {
      const u16* vp = Vh + (size_t)(dt * 16 + l15) * SEQ + mb + l4 * 8;
      f16x8 vb = *(const f16x8*)vp;
      oacc[dt] = mfma16(pa, vb, oacc[dt]);
    }
  }
  __syncthreads();                 // P fully consumed -> S reusable for fp32 partials
  float* Op = (float*)S;           // [16 waves][16 rows][stride 65] fp32 = 66.5 KB
#pragma unroll
  for (int dt = 0; dt < 4; dt++)
#pragma unroll
    for (int j = 0; j < 4; j++)
      Op[(wave * 16 + l4 * 4 + j) * 65 + dt * 16 + l15] = oacc[dt][j];
  __syncthreads();
  {
    int row = tid >> 6, d = tid & 63;   // exactly 1024 outputs
    float v = 0.f;
#pragma unroll
    for (int w = 0; w < 16; ++w) v += Op[(w * 16 + row) * 65 + d];
    Ob[((size_t)b * SEQ + q0 + row) * DIMC + h * HDIM + d] = f2h_bits(v);
  }
}

// ---------------- launch ----------------
extern "C" void kernel_launch(void* const* d_in, const int* in_sizes, int n_in,
                              void* d_out, int out_size, void* d_ws, size_t ws_size,
                              hipStream_t stream) {
  const float* x  = (const float*)d_in[0];
  const float* Wq = (const float*)d_in[1];
  const float* Wk = (const float*)d_in[2];
  const float* Wv = (const float*)d_in[3];
  const float* Wp = (const float*)d_in[4];
  const float* bp = (const float*)d_in[5];
  float* out = (float*)d_out;

  const size_t M = 2 * (size_t)SEQ;            // 8192
  const size_t XB = M * DIMC * 2;              // fp16 x / Q / K / Vt / O buffers
  const size_t WB = (size_t)DIMC * DIMC * 2;

  char* w = (char*)d_ws;
  u16* xb   = (u16*)w; w += XB;
  u16* Wqb  = (u16*)w; w += WB;
  u16* Wkb  = (u16*)w; w += WB;
  u16* Wvb  = (u16*)w; w += WB;
  u16* Wpb  = (u16*)w; w += WB;
  u16* Qb   = (u16*)w; w += XB;
  u16* Kbuf = (u16*)w; w += XB;
  u16* Vtb  = (u16*)w; w += XB;
  u16* Obuf = (u16*)w; w += XB;

  cast_f32_to_f16<<<6144, 256, 0, stream>>>(x,  xb,  (int)(M * DIMC / 4));
  cast_f32_to_f16<<<576,  256, 0, stream>>>(Wq, Wqb, (int)(WB / 8));
  cast_f32_to_f16<<<576,  256, 0, stream>>>(Wk, Wkb, (int)(WB / 8));
  cast_f32_to_f16<<<576,  256, 0, stream>>>(Wv, Wvb, (int)(WB / 8));
  cast_f32_to_f16<<<576,  256, 0, stream>>>(Wp, Wpb, (int)(WB / 8));

  dim3 gg(64, 6);
  gemm_nt<0><<<gg, 256, 0, stream>>>(xb, Wqb, 0.125f, nullptr, Qb);    // Q pre-scaled
  gemm_nt<0><<<gg, 256, 0, stream>>>(xb, Wkb, 1.0f,   nullptr, Kbuf);
  gemm_nt<1><<<gg, 256, 0, stream>>>(xb, Wvb, 1.0f,   nullptr, Vtb);   // V transposed

  attn_kernel<<<dim3(256, NHEADS, 2), 1024, 0, stream>>>(Qb, Kbuf, Vtb, Obuf);

  gemm_nt<2><<<gg, 256, 0, stream>>>(Obuf, Wpb, 1.0f, bp, out);
}

// Round 3
// 1696.844 us; speedup vs baseline: 1.5080x; 1.1563x over previous
//
#include <hip/hip_runtime.h>

// SparseFinerAttention on MI355X — round 3 (kill scratch spill: VGPR budget + packed keys)
// B=2 N=4096 C=768 H=12 D=64 SCALE=1/8 K_keep=409
//
// Pipeline: cast->fp16; Q/K/V NT-GEMMs (MFMA 16x16x32_f16); fused attention
// (QK^T -> exact top-k on quantized logits -> masked dense PV); out GEMM+bias.

typedef unsigned short u16;
typedef unsigned int   u32;
typedef float    f32x4 __attribute__((ext_vector_type(4)));
typedef _Float16 f16x8 __attribute__((ext_vector_type(8)));
typedef u16      u16x8 __attribute__((ext_vector_type(8)));
typedef u16      u16x4 __attribute__((ext_vector_type(4)));

#define NHEADS 12
#define SEQ    4096
#define DIMC   768
#define HDIM   64
#define KKEEP  409

__device__ __forceinline__ f32x4 mfma16(f16x8 a, f16x8 b, f32x4 c) {
  return __builtin_amdgcn_mfma_f32_16x16x32_f16(a, b, c, 0, 0, 0);
}
__device__ __forceinline__ u16 f2h_bits(float f) {
  return __builtin_bit_cast(u16, (_Float16)f);
}
__device__ __forceinline__ float h2f_bits(u16 b) {
  return (float)__builtin_bit_cast(_Float16, b);
}

// ---------------- cast fp32 -> fp16 (vectorized) ----------------
__global__ __launch_bounds__(256) void cast_f32_to_f16(const float* __restrict__ in,
                                                       u16* __restrict__ out, int n4) {
  int i = blockIdx.x * 256 + threadIdx.x;
  if (i >= n4) return;
  float4 v = ((const float4*)in)[i];
  u16x4 o;
  o[0] = f2h_bits(v.x); o[1] = f2h_bits(v.y); o[2] = f2h_bits(v.z); o[3] = f2h_bits(v.w);
  ((u16x4*)out)[i] = o;
}

// ---------------- NT GEMM: C[M][768] = A[M][768] @ B[768][768]^T ----------------
// MODE 0: store fp16, head layout dst[b][h][n][d], value*scale   (Q with scale=0.125, K scale=1)
// MODE 1: store fp16, transposed head layout dst[b][h][d][n]     (V)
// MODE 2: store fp32 + bias, flat [M][768]                       (final projection)
template<int MODE>
__global__ __launch_bounds__(256) void gemm_nt(const u16* __restrict__ A, const u16* __restrict__ B,
                                               float scale, const float* __restrict__ bias,
                                               void* __restrict__ dstv) {
  __shared__ __align__(16) u16 As[128 * 64];
  __shared__ __align__(16) u16 Bs[128 * 64];
  const int tid  = threadIdx.x;
  const int lane = tid & 63, wave = tid >> 6;
  const int l15 = lane & 15, l4 = lane >> 4;
  const int row0 = blockIdx.x * 128, col0 = blockIdx.y * 128;
  const int wr = (wave >> 1) * 64, wc = (wave & 1) * 64;
  f32x4 acc[4][4];
#pragma unroll
  for (int i = 0; i < 4; i++)
#pragma unroll
    for (int j = 0; j < 4; j++) acc[i][j] = f32x4{0.f, 0.f, 0.f, 0.f};

  for (int k0 = 0; k0 < DIMC; k0 += 64) {
#pragma unroll
    for (int i = 0; i < 4; i++) {
      int id = tid + i * 256;
      int r = id >> 3, c = id & 7;
      f16x8 va = *(const f16x8*)(A + (size_t)(row0 + r) * DIMC + k0 + c * 8);
      f16x8 vb = *(const f16x8*)(B + (size_t)(col0 + r) * DIMC + k0 + c * 8);
      *(f16x8*)(As + r * 64 + ((c ^ (r & 7)) << 3)) = va;
      *(f16x8*)(Bs + r * 64 + ((c ^ (r & 7)) << 3)) = vb;
    }
    __syncthreads();
#pragma unroll
    for (int ks = 0; ks < 2; ++ks) {
      f16x8 af[4], bfr[4];
#pragma unroll
      for (int i = 0; i < 4; i++) {
        int r = wr + i * 16 + l15;
        int c = ks * 4 + l4;
        af[i] = *(const f16x8*)(As + r * 64 + ((c ^ (r & 7)) << 3));
        int r2 = wc + i * 16 + l15;
        bfr[i] = *(const f16x8*)(Bs + r2 * 64 + ((c ^ (r2 & 7)) << 3));
      }
#pragma unroll
      for (int i = 0; i < 4; i++)
#pragma unroll
        for (int j = 0; j < 4; j++) acc[i][j] = mfma16(af[i], bfr[j], acc[i][j]);
    }
    __syncthreads();
  }

  // epilogue: C/D layout col=lane&15, row=(lane>>4)*4+jj  [m89-verified]
#pragma unroll
  for (int i = 0; i < 4; i++) {
#pragma unroll
    for (int j = 0; j < 4; j++) {
      int rowb = row0 + wr + i * 16 + (l4 << 2);
      int col  = col0 + wc + j * 16 + l15;
      if (MODE == 2) {
        float* dst = (float*)dstv;
        float bv = bias[col];
#pragma unroll
        for (int jj = 0; jj < 4; jj++)
          dst[(size_t)(rowb + jj) * DIMC + col] = acc[i][j][jj] + bv;
      } else if (MODE == 0) {
        u16* dst = (u16*)dstv;
        int hh = col >> 6, d = col & 63;
#pragma unroll
        for (int jj = 0; jj < 4; jj++) {
          int row = rowb + jj;
          int bb = row >> 12, n = row & 4095;
          dst[(((size_t)bb * NHEADS + hh) * SEQ + n) * HDIM + d] = f2h_bits(acc[i][j][jj] * scale);
        }
      } else { // MODE 1: V transposed [b][h][d][n]
        u16* dst = (u16*)dstv;
        int hh = col >> 6, d = col & 63;
        int bb = rowb >> 12, nb = rowb & 4095;
        u16x4 pack;
#pragma unroll
        for (int jj = 0; jj < 4; jj++) pack[jj] = f2h_bits(acc[i][j][jj] * scale);
        *(u16x4*)(dst + (((size_t)bb * NHEADS + hh) * HDIM + d) * SEQ + nb) = pack;
      }
    }
  }
}

// ---------------- fused attention: QK^T -> softmax + exact top-k -> masked PV ----------------
// 1 workgroup (1024 thr, 16 waves) per (b, h, 16-row q block).
// QK^T:    wave w computes keys [w*256, (w+1)*256) via swapped mfma(K,Q) -> u16x4 LDS writes.
// top-k:   wave w owns row w; keys register-cached PACKED 2-per-u32 (32 VGPRs, no spill).
// PV:      wave w covers its 256 keys; fp32 partials aliased into S after barrier.
// S: [16][4096] fp16, XOR-swizzled: sidx(q,m) = q*4096 + (((m>>3) ^ (q&7))<<3 | (m&7))
__global__ __launch_bounds__(1024, 4) void attn_kernel(const u16* __restrict__ Q, const u16* __restrict__ Kb,
                                                       const u16* __restrict__ Vt, u16* __restrict__ Ob) {
  __shared__ __align__(16) u16 S[16 * 4096];      // 128 KB (re-used for fp32 O-partials)
  const int tid  = threadIdx.x;
  const int lane = tid & 63, wave = tid >> 6;
  const int l15 = lane & 15, l4 = lane >> 4;
  const int h = blockIdx.y, b = blockIdx.z;
  const int bh = b * NHEADS + h;
  const int q0 = blockIdx.x * 16;
  const u16* Qh = Q  + ((size_t)bh * SEQ + q0) * HDIM;
  const u16* Kh = Kb + (size_t)bh * SEQ * HDIM;
  const u16* Vh = Vt + (size_t)bh * HDIM * SEQ;

  // Q fragments (rows q0..q0+15), Q already pre-scaled by 1/8. B-operand: l15 = q row.
  f16x8 qa0 = *(const f16x8*)(Qh + l15 * HDIM + l4 * 8);
  f16x8 qa1 = *(const f16x8*)(Qh + l15 * HDIM + 32 + l4 * 8);

  // ---- QK^T (swapped): wave w covers keys [w*256, (w+1)*256) ----
  // mfma(K,Q): out row (l4*4+j) = key-within-16, col (l15) = q row.
  const int m0base = wave * 256;
#pragma unroll 2
  for (int t = 0; t < 16; ++t) {
    int m0 = m0base + t * 16;
    const u16* kp = Kh + (size_t)(m0 + l15) * HDIM + l4 * 8;
    f16x8 kb0 = *(const f16x8*)kp;
    f16x8 kb1 = *(const f16x8*)(kp + 32);
    f32x4 acc = f32x4{0.f, 0.f, 0.f, 0.f};
    acc = mfma16(kb0, qa0, acc);
    acc = mfma16(kb1, qa1, acc);
    // lane holds keys m0 + l4*4 + {0..3} of q-row l15 -> one u16x4 store
    int g = (m0 >> 3) + (l4 >> 1);            // 8-key group index
    u16x4 pack;
#pragma unroll
    for (int j = 0; j < 4; j++) pack[j] = f2h_bits(acc[j]);
    *(u16x4*)(S + (l15 << 12) + ((g ^ (l15 & 7)) << 3) + ((l4 & 1) << 2)) = pack;
  }
  __syncthreads();

  // ---- per-row softmax denom + exact top-k(409) threshold; wave w owns row w ----
  {
    const int row = wave;
    const u32 rbase = (u32)row << 12;
    const u32 rx = (u32)(row & 7) << 3;
    // register-cache the row as order-preserving u16 keys, PACKED 2 per u32.
    // lane owns chunks c = cc*64+lane; element order within chunk preserved:
    // key(e=2p)   = kp[cc][p] & 0xFFFF,  key(e=2p+1) = kp[cc][p] >> 16
    u32 kp[8][4];
#pragma unroll
    for (int cc = 0; cc < 8; ++cc) {
      u32 c = (u32)cc * 64 + lane;
      u16x8 v = *(const u16x8*)(S + rbase + ((c << 3) ^ rx));
#pragma unroll
      for (int p = 0; p < 4; p++) {
        u32 u0 = v[2 * p], u1 = v[2 * p + 1];
        u0 = (u0 & 0x8000u) ? (u0 ^ 0xFFFFu) : (u0 | 0x8000u);
        u1 = (u1 & 0x8000u) ? (u1 ^ 0xFFFFu) : (u1 | 0x8000u);
        kp[cc][p] = u0 | (u1 << 16);
      }
    }
    // binary search: smallest t with count(key > t) < KKEEP  => t = Kth-largest key
    u32 lo = 0, hi = 65535;
    while (lo < hi) {
      u32 mid = (lo + hi) >> 1;
      int cnt = 0;
#pragma unroll
      for (int cc = 0; cc < 8; ++cc)
#pragma unroll
        for (int p = 0; p < 4; p++) {
          u32 pr = kp[cc][p];
          cnt += ((pr & 0xFFFFu) > mid) ? 1 : 0;
          cnt += ((pr >> 16) > mid) ? 1 : 0;
        }
#pragma unroll
      for (int o = 32; o; o >>= 1) cnt += __shfl_xor(cnt, o);
      if (cnt < KKEEP) hi = mid; else lo = mid + 1;
    }
    const u32 t = lo;
    // stats: count > t, and softmax denom Z = sum exp(l)  (logits ~O(1): no max-sub needed)
    int c1 = 0; float z = 0.f;
#pragma unroll
    for (int cc = 0; cc < 8; ++cc)
#pragma unroll
      for (int p = 0; p < 4; p++) {
        u32 pr = kp[cc][p];
        u32 k0 = pr & 0xFFFFu, k1 = pr >> 16;
        c1 += (k0 > t) ? 1 : 0;
        c1 += (k1 > t) ? 1 : 0;
        u16 h0 = (k0 & 0x8000u) ? (u16)(k0 ^ 0x8000u) : (u16)(k0 ^ 0xFFFFu);
        u16 h1 = (k1 & 0x8000u) ? (u16)(k1 ^ 0x8000u) : (u16)(k1 ^ 0xFFFFu);
        z += __expf(h2f_bits(h0));
        z += __expf(h2f_bits(h1));
      }
#pragma unroll
    for (int o = 32; o; o >>= 1) { c1 += __shfl_xor(c1, o); z += __shfl_xor(z, o); }
    const float invZ = 1.f / z;
    const int r = KKEEP - c1;   // how many ==t entries to keep (lowest index first)
    // rank of ==t entries in m-order: m = (cc*64+lane)*8 + e -> lexicographic (cc, lane, e)
    int lanepre[8], eqtot[8];
#pragma unroll
    for (int cc = 0; cc < 8; ++cc) {
      int ec = 0;
#pragma unroll
      for (int p = 0; p < 4; p++) {
        u32 pr = kp[cc][p];
        ec += ((pr & 0xFFFFu) == t) ? 1 : 0;
        ec += ((pr >> 16) == t) ? 1 : 0;
      }
      int inc = ec;
#pragma unroll
      for (int o = 1; o < 64; o <<= 1) { int pfx = __shfl_up(inc, o); if (lane >= o) inc += pfx; }
      lanepre[cc] = inc - ec;
      eqtot[cc]   = __shfl(inc, 63);
    }
    int run = 0, rank0[8];
#pragma unroll
    for (int cc = 0; cc < 8; ++cc) { rank0[cc] = run + lanepre[cc]; run += eqtot[cc]; }
    // write back masked softmax weights (fp16) in place
#pragma unroll
    for (int cc = 0; cc < 8; ++cc) {
      int rk = rank0[cc];
      u16x8 wv;
#pragma unroll
      for (int p = 0; p < 4; p++) {
#pragma unroll
        for (int half = 0; half < 2; half++) {
          u32 k = half ? (kp[cc][p] >> 16) : (kp[cc][p] & 0xFFFFu);
          bool keep;
          if (k > t) keep = true;
          else if (k == t) { keep = (rk < r); rk++; }
          else keep = false;
          float w = 0.f;
          if (keep) {
            u16 hb = (k & 0x8000u) ? (u16)(k ^ 0x8000u) : (u16)(k ^ 0xFFFFu);
            w = __expf(h2f_bits(hb)) * invZ;
          }
          wv[2 * p + half] = f2h_bits(w);
        }
      }
      u32 c = (u32)cc * 64 + lane;
      *(u16x8*)(S + rbase + ((c << 3) ^ rx)) = wv;
    }
  }
  __syncthreads();

  // ---- masked dense PV: O[16][64] += P[16][m-range] @ V^T; wave w covers its 256 keys ----
  f32x4 oacc[4];
#pragma unroll
  for (int dt = 0; dt < 4; dt++) oacc[dt] = f32x4{0.f, 0.f, 0.f, 0.f};
#pragma unroll 2
  for (int ks = 0; ks < 8; ++ks) {
    int mb = wave * 256 + ks * 32;
    u32 c = (u32)(mb >> 3) + l4;
    f16x8 pa = *(const f16x8*)(S + (l15 << 12) + (((c ^ (l15 & 7))) << 3));
#pragma unroll
    for (int dt = 0; dt < 4; ++dt) {
      const u16* vp = Vh + (size_t)(dt * 16 + l15) * SEQ + mb + l4 * 8;
      f16x8 vb = *(const f16x8*)vp;
      oacc[dt] = mfma16(pa, vb, oacc[dt]);
    }
  }
  __syncthreads();                 // P fully consumed -> S reusable for fp32 partials
  float* Op = (float*)S;           // [16 waves][16 rows][stride 65] fp32 = 66.5 KB
#pragma unroll
  for (int dt = 0; dt < 4; dt++)
#pragma unroll
    for (int j = 0; j < 4; j++)
      Op[(wave * 16 + l4 * 4 + j) * 65 + dt * 16 + l15] = oacc[dt][j];
  __syncthreads();
  {
    int row = tid >> 6, d = tid & 63;   // exactly 1024 outputs
    float v = 0.f;
#pragma unroll
    for (int w = 0; w < 16; ++w) v += Op[(w * 16 + row) * 65 + d];
    Ob[((size_t)b * SEQ + q0 + row) * DIMC + h * HDIM + d] = f2h_bits(v);
  }
}

// ---------------- launch ----------------
extern "C" void kernel_launch(void* const* d_in, const int* in_sizes, int n_in,
                              void* d_out, int out_size, void* d_ws, size_t ws_size,
                              hipStream_t stream) {
  const float* x  = (const float*)d_in[0];
  const float* Wq = (const float*)d_in[1];
  const float* Wk = (const float*)d_in[2];
  const float* Wv = (const float*)d_in[3];
  const float* Wp = (const float*)d_in[4];
  const float* bp = (const float*)d_in[5];
  float* out = (float*)d_out;

  const size_t M = 2 * (size_t)SEQ;            // 8192
  const size_t XB = M * DIMC * 2;              // fp16 x / Q / K / Vt / O buffers
  const size_t WB = (size_t)DIMC * DIMC * 2;

  char* w = (char*)d_ws;
  u16* xb   = (u16*)w; w += XB;
  u16* Wqb  = (u16*)w; w += WB;
  u16* Wkb  = (u16*)w; w += WB;
  u16* Wvb  = (u16*)w; w += WB;
  u16* Wpb  = (u16*)w; w += WB;
  u16* Qb   = (u16*)w; w += XB;
  u16* Kbuf = (u16*)w; w += XB;
  u16* Vtb  = (u16*)w; w += XB;
  u16* Obuf = (u16*)w; w += XB;

  cast_f32_to_f16<<<6144, 256, 0, stream>>>(x,  xb,  (int)(M * DIMC / 4));
  cast_f32_to_f16<<<576,  256, 0, stream>>>(Wq, Wqb, (int)(WB / 8));
  cast_f32_to_f16<<<576,  256, 0, stream>>>(Wk, Wkb, (int)(WB / 8));
  cast_f32_to_f16<<<576,  256, 0, stream>>>(Wv, Wvb, (int)(WB / 8));
  cast_f32_to_f16<<<576,  256, 0, stream>>>(Wp, Wpb, (int)(WB / 8));

  dim3 gg(64, 6);
  gemm_nt<0><<<gg, 256, 0, stream>>>(xb, Wqb, 0.125f, nullptr, Qb);    // Q pre-scaled
  gemm_nt<0><<<gg, 256, 0, stream>>>(xb, Wkb, 1.0f,   nullptr, Kbuf);
  gemm_nt<1><<<gg, 256, 0, stream>>>(xb, Wvb, 1.0f,   nullptr, Vtb);   // V transposed

  attn_kernel<<<dim3(256, NHEADS, 2), 1024, 0, stream>>>(Qb, Kbuf, Vtb, Obuf);

  gemm_nt<2><<<gg, 256, 0, stream>>>(Obuf, Wpb, 1.0f, bp, out);
}

// Round 4
// 1671.634 us; speedup vs baseline: 1.5307x; 1.0151x over previous
//
#include <hip/hip_runtime.h>

// SparseFinerAttention on MI355X — round 4 (fit select phase in 64 VGPRs: no spill)
// B=2 N=4096 C=768 H=12 D=64 SCALE=1/8 K_keep=409
//
// Pipeline: cast->fp16; Q/K/V NT-GEMMs (MFMA 16x16x32_f16); fused attention
// (QK^T -> exact top-k on quantized logits -> masked dense PV); out GEMM+bias.

typedef unsigned short u16;
typedef unsigned int   u32;
typedef float    f32x4 __attribute__((ext_vector_type(4)));
typedef _Float16 f16x8 __attribute__((ext_vector_type(8)));
typedef u16      u16x8 __attribute__((ext_vector_type(8)));
typedef u16      u16x4 __attribute__((ext_vector_type(4)));

#define NHEADS 12
#define SEQ    4096
#define DIMC   768
#define HDIM   64
#define KKEEP  409

__device__ __forceinline__ f32x4 mfma16(f16x8 a, f16x8 b, f32x4 c) {
  return __builtin_amdgcn_mfma_f32_16x16x32_f16(a, b, c, 0, 0, 0);
}
__device__ __forceinline__ u16 f2h_bits(float f) {
  return __builtin_bit_cast(u16, (_Float16)f);
}
__device__ __forceinline__ float h2f_bits(u16 b) {
  return (float)__builtin_bit_cast(_Float16, b);
}

// ---------------- cast fp32 -> fp16 (vectorized) ----------------
__global__ __launch_bounds__(256) void cast_f32_to_f16(const float* __restrict__ in,
                                                       u16* __restrict__ out, int n4) {
  int i = blockIdx.x * 256 + threadIdx.x;
  if (i >= n4) return;
  float4 v = ((const float4*)in)[i];
  u16x4 o;
  o[0] = f2h_bits(v.x); o[1] = f2h_bits(v.y); o[2] = f2h_bits(v.z); o[3] = f2h_bits(v.w);
  ((u16x4*)out)[i] = o;
}

// ---------------- NT GEMM: C[M][768] = A[M][768] @ B[768][768]^T ----------------
// MODE 0: store fp16, head layout dst[b][h][n][d], value*scale   (Q with scale=0.125, K scale=1)
// MODE 1: store fp16, transposed head layout dst[b][h][d][n]     (V)
// MODE 2: store fp32 + bias, flat [M][768]                       (final projection)
template<int MODE>
__global__ __launch_bounds__(256) void gemm_nt(const u16* __restrict__ A, const u16* __restrict__ B,
                                               float scale, const float* __restrict__ bias,
                                               void* __restrict__ dstv) {
  __shared__ __align__(16) u16 As[128 * 64];
  __shared__ __align__(16) u16 Bs[128 * 64];
  const int tid  = threadIdx.x;
  const int lane = tid & 63, wave = tid >> 6;
  const int l15 = lane & 15, l4 = lane >> 4;
  const int row0 = blockIdx.x * 128, col0 = blockIdx.y * 128;
  const int wr = (wave >> 1) * 64, wc = (wave & 1) * 64;
  f32x4 acc[4][4];
#pragma unroll
  for (int i = 0; i < 4; i++)
#pragma unroll
    for (int j = 0; j < 4; j++) acc[i][j] = f32x4{0.f, 0.f, 0.f, 0.f};

  for (int k0 = 0; k0 < DIMC; k0 += 64) {
#pragma unroll
    for (int i = 0; i < 4; i++) {
      int id = tid + i * 256;
      int r = id >> 3, c = id & 7;
      f16x8 va = *(const f16x8*)(A + (size_t)(row0 + r) * DIMC + k0 + c * 8);
      f16x8 vb = *(const f16x8*)(B + (size_t)(col0 + r) * DIMC + k0 + c * 8);
      *(f16x8*)(As + r * 64 + ((c ^ (r & 7)) << 3)) = va;
      *(f16x8*)(Bs + r * 64 + ((c ^ (r & 7)) << 3)) = vb;
    }
    __syncthreads();
#pragma unroll
    for (int ks = 0; ks < 2; ++ks) {
      f16x8 af[4], bfr[4];
#pragma unroll
      for (int i = 0; i < 4; i++) {
        int r = wr + i * 16 + l15;
        int c = ks * 4 + l4;
        af[i] = *(const f16x8*)(As + r * 64 + ((c ^ (r & 7)) << 3));
        int r2 = wc + i * 16 + l15;
        bfr[i] = *(const f16x8*)(Bs + r2 * 64 + ((c ^ (r2 & 7)) << 3));
      }
#pragma unroll
      for (int i = 0; i < 4; i++)
#pragma unroll
        for (int j = 0; j < 4; j++) acc[i][j] = mfma16(af[i], bfr[j], acc[i][j]);
    }
    __syncthreads();
  }

  // epilogue: C/D layout col=lane&15, row=(lane>>4)*4+jj  [m89-verified]
#pragma unroll
  for (int i = 0; i < 4; i++) {
#pragma unroll
    for (int j = 0; j < 4; j++) {
      int rowb = row0 + wr + i * 16 + (l4 << 2);
      int col  = col0 + wc + j * 16 + l15;
      if (MODE == 2) {
        float* dst = (float*)dstv;
        float bv = bias[col];
#pragma unroll
        for (int jj = 0; jj < 4; jj++)
          dst[(size_t)(rowb + jj) * DIMC + col] = acc[i][j][jj] + bv;
      } else if (MODE == 0) {
        u16* dst = (u16*)dstv;
        int hh = col >> 6, d = col & 63;
#pragma unroll
        for (int jj = 0; jj < 4; jj++) {
          int row = rowb + jj;
          int bb = row >> 12, n = row & 4095;
          dst[(((size_t)bb * NHEADS + hh) * SEQ + n) * HDIM + d] = f2h_bits(acc[i][j][jj] * scale);
        }
      } else { // MODE 1: V transposed [b][h][d][n]
        u16* dst = (u16*)dstv;
        int hh = col >> 6, d = col & 63;
        int bb = rowb >> 12, nb = rowb & 4095;
        u16x4 pack;
#pragma unroll
        for (int jj = 0; jj < 4; jj++) pack[jj] = f2h_bits(acc[i][j][jj] * scale);
        *(u16x4*)(dst + (((size_t)bb * NHEADS + hh) * HDIM + d) * SEQ + nb) = pack;
      }
    }
  }
}

// ---------------- fused attention: QK^T -> softmax + exact top-k -> masked PV ----------------
// 1 workgroup (1024 thr, 16 waves) per (b, h, 16-row q block).
// QK^T:    wave w computes keys [w*256, (w+1)*256) via swapped mfma(K,Q), explicit K prefetch.
// top-k:   wave w owns row w; keys PACKED 2-per-u32 (32 VGPRs); tie-rank STREAMED (scalars,
//          not arrays) so peak live regs stay < 64 — round-3 spilled ~19 regs here.
// PV:      wave w covers its 256 keys; fp32 partials aliased into S after barrier.
// S: [16][4096] fp16, XOR-swizzled: sidx(q,m) = q*4096 + (((m>>3) ^ (q&7))<<3 | (m&7))
__global__ __launch_bounds__(1024, 4) void attn_kernel(const u16* __restrict__ Q, const u16* __restrict__ Kb,
                                                       const u16* __restrict__ Vt, u16* __restrict__ Ob) {
  __shared__ __align__(16) u16 S[16 * 4096];      // 128 KB (re-used for fp32 O-partials)
  const int tid  = threadIdx.x;
  const int lane = tid & 63, wave = tid >> 6;
  const int l15 = lane & 15, l4 = lane >> 4;
  const int h = blockIdx.y, b = blockIdx.z;
  const int bh = b * NHEADS + h;
  const int q0 = blockIdx.x * 16;
  const u16* Qh = Q  + ((size_t)bh * SEQ + q0) * HDIM;
  const u16* Kh = Kb + (size_t)bh * SEQ * HDIM;
  const u16* Vh = Vt + (size_t)bh * HDIM * SEQ;

  // Q fragments (rows q0..q0+15), Q already pre-scaled by 1/8. B-operand: l15 = q row.
  f16x8 qa0 = *(const f16x8*)(Qh + l15 * HDIM + l4 * 8);
  f16x8 qa1 = *(const f16x8*)(Qh + l15 * HDIM + 32 + l4 * 8);

  // ---- QK^T (swapped): wave w covers keys [w*256, (w+1)*256) ----
  // mfma(K,Q): out row (l4*4+j) = key-within-16, col (l15) = q row.
  // Single-step explicit prefetch; no unroll (keeps live regs ~50).
  const int m0base = wave * 256;
  {
    const u16* kptr = Kh + (size_t)(m0base + l15) * HDIM + l4 * 8;
    f16x8 kb0 = *(const f16x8*)kptr;
    f16x8 kb1 = *(const f16x8*)(kptr + 32);
#pragma unroll 1
    for (int t = 0; t < 16; ++t) {
      f16x8 cur0 = kb0, cur1 = kb1;
      if (t < 15) {
        const u16* kpn = Kh + (size_t)(m0base + (t + 1) * 16 + l15) * HDIM + l4 * 8;
        kb0 = *(const f16x8*)kpn;
        kb1 = *(const f16x8*)(kpn + 32);
      }
      f32x4 acc = f32x4{0.f, 0.f, 0.f, 0.f};
      acc = mfma16(cur0, qa0, acc);
      acc = mfma16(cur1, qa1, acc);
      // lane holds keys m0 + l4*4 + {0..3} of q-row l15 -> one u16x4 store
      int m0 = m0base + t * 16;
      int g = (m0 >> 3) + (l4 >> 1);            // 8-key group index
      u16x4 pack;
#pragma unroll
      for (int j = 0; j < 4; j++) pack[j] = f2h_bits(acc[j]);
      *(u16x4*)(S + (l15 << 12) + ((g ^ (l15 & 7)) << 3) + ((l4 & 1) << 2)) = pack;
    }
  }
  __syncthreads();

  // ---- per-row softmax denom + exact top-k(409) threshold; wave w owns row w ----
  {
    const int row = wave;
    const u32 rbase = (u32)row << 12;
    const u32 rx = (u32)(row & 7) << 3;
    // register-cache the row as order-preserving u16 keys, PACKED 2 per u32.
    // lane owns chunks c = cc*64+lane; element order within chunk preserved:
    // key(e=2p)   = kp[cc][p] & 0xFFFF,  key(e=2p+1) = kp[cc][p] >> 16
    u32 kp[8][4];
#pragma unroll
    for (int cc = 0; cc < 8; ++cc) {
      u32 c = (u32)cc * 64 + lane;
      u16x8 v = *(const u16x8*)(S + rbase + ((c << 3) ^ rx));
#pragma unroll
      for (int p = 0; p < 4; p++) {
        u32 u0 = v[2 * p], u1 = v[2 * p + 1];
        u0 = (u0 & 0x8000u) ? (u0 ^ 0xFFFFu) : (u0 | 0x8000u);
        u1 = (u1 & 0x8000u) ? (u1 ^ 0xFFFFu) : (u1 | 0x8000u);
        kp[cc][p] = u0 | (u1 << 16);
      }
    }
    // binary search: smallest t with count(key > t) < KKEEP  => t = Kth-largest key
    u32 lo = 0, hi = 65535;
    while (lo < hi) {
      u32 mid = (lo + hi) >> 1;
      int cnt = 0;
#pragma unroll
      for (int cc = 0; cc < 8; ++cc)
#pragma unroll
        for (int p = 0; p < 4; p++) {
          u32 pr = kp[cc][p];
          cnt += ((pr & 0xFFFFu) > mid) ? 1 : 0;
          cnt += ((pr >> 16) > mid) ? 1 : 0;
        }
#pragma unroll
      for (int o = 32; o; o >>= 1) cnt += __shfl_xor(cnt, o);
      if (cnt < KKEEP) hi = mid; else lo = mid + 1;
    }
    const u32 t = lo;
    // stats: count > t, and softmax denom Z = sum exp(l)  (logits ~O(1): no max-sub needed)
    int c1 = 0; float z = 0.f;
#pragma unroll
    for (int cc = 0; cc < 8; ++cc)
#pragma unroll
      for (int p = 0; p < 4; p++) {
        u32 pr = kp[cc][p];
        u32 k0 = pr & 0xFFFFu, k1 = pr >> 16;
        c1 += (k0 > t) ? 1 : 0;
        c1 += (k1 > t) ? 1 : 0;
        u16 h0 = (k0 & 0x8000u) ? (u16)(k0 ^ 0x8000u) : (u16)(k0 ^ 0xFFFFu);
        u16 h1 = (k1 & 0x8000u) ? (u16)(k1 ^ 0x8000u) : (u16)(k1 ^ 0xFFFFu);
        z += __expf(h2f_bits(h0));
        z += __expf(h2f_bits(h1));
      }
#pragma unroll
    for (int o = 32; o; o >>= 1) { c1 += __shfl_xor(c1, o); z += __shfl_xor(z, o); }
    const float invZ = 1.f / z;
    const int r = KKEEP - c1;   // how many ==t entries to keep (lowest index first)
    // STREAMED tie-rank + write-back: per chunk cc, rank of ==t entries in m-order
    // (m = (cc*64+lane)*8+e is lexicographic in (cc, lane, e)), carried by `run`.
    int run = 0;
#pragma unroll 1
    for (int cc = 0; cc < 8; ++cc) {
      int ec = 0;
#pragma unroll
      for (int p = 0; p < 4; p++) {
        u32 pr = kp[cc][p];
        ec += ((pr & 0xFFFFu) == t) ? 1 : 0;
        ec += ((pr >> 16) == t) ? 1 : 0;
      }
      int inc = ec;
#pragma unroll
      for (int o = 1; o < 64; o <<= 1) { int pfx = __shfl_up(inc, o); if (lane >= o) inc += pfx; }
      int rk = run + inc - ec;          // this lane's first ==t rank within row
      run += __shfl(inc, 63);           // row-wide ==t total so far
      u16x8 wv;
#pragma unroll
      for (int p = 0; p < 4; p++) {
#pragma unroll
        for (int half = 0; half < 2; half++) {
          u32 k = half ? (kp[cc][p] >> 16) : (kp[cc][p] & 0xFFFFu);
          bool keep;
          if (k > t) keep = true;
          else if (k == t) { keep = (rk < r); rk++; }
          else keep = false;
          float w = 0.f;
          if (keep) {
            u16 hb = (k & 0x8000u) ? (u16)(k ^ 0x8000u) : (u16)(k ^ 0xFFFFu);
            w = __expf(h2f_bits(hb)) * invZ;
          }
          wv[2 * p + half] = f2h_bits(w);
        }
      }
      u32 c = (u32)cc * 64 + lane;
      *(u16x8*)(S + rbase + ((c << 3) ^ rx)) = wv;
    }
  }
  __syncthreads();

  // ---- masked dense PV: O[16][64] += P[16][m-range] @ V^T; wave w covers its 256 keys ----
  f32x4 oacc[4];
#pragma unroll
  for (int dt = 0; dt < 4; dt++) oacc[dt] = f32x4{0.f, 0.f, 0.f, 0.f};
#pragma unroll 1
  for (int ks = 0; ks < 8; ++ks) {
    int mb = wave * 256 + ks * 32;
    u32 c = (u32)(mb >> 3) + l4;
    f16x8 pa = *(const f16x8*)(S + (l15 << 12) + (((c ^ (l15 & 7))) << 3));
#pragma unroll
    for (int dt = 0; dt < 4; ++dt) {
      const u16* vp = Vh + (size_t)(dt * 16 + l15) * SEQ + mb + l4 * 8;
      f16x8 vb = *(const f16x8*)vp;
      oacc[dt] = mfma16(pa, vb, oacc[dt]);
    }
  }
  __syncthreads();                 // P fully consumed -> S reusable for fp32 partials
  float* Op = (float*)S;           // [16 waves][16 rows][stride 65] fp32 = 66.5 KB
#pragma unroll
  for (int dt = 0; dt < 4; dt++)
#pragma unroll
    for (int j = 0; j < 4; j++)
      Op[(wave * 16 + l4 * 4 + j) * 65 + dt * 16 + l15] = oacc[dt][j];
  __syncthreads();
  {
    int row = tid >> 6, d = tid & 63;   // exactly 1024 outputs
    float v = 0.f;
#pragma unroll
    for (int w = 0; w < 16; ++w) v += Op[(w * 16 + row) * 65 + d];
    Ob[((size_t)b * SEQ + q0 + row) * DIMC + h * HDIM + d] = f2h_bits(v);
  }
}

// ---------------- launch ----------------
extern "C" void kernel_launch(void* const* d_in, const int* in_sizes, int n_in,
                              void* d_out, int out_size, void* d_ws, size_t ws_size,
                              hipStream_t stream) {
  const float* x  = (const float*)d_in[0];
  const float* Wq = (const float*)d_in[1];
  const float* Wk = (const float*)d_in[2];
  const float* Wv = (const float*)d_in[3];
  const float* Wp = (const float*)d_in[4];
  const float* bp = (const float*)d_in[5];
  float* out = (float*)d_out;

  const size_t M = 2 * (size_t)SEQ;            // 8192
  const size_t XB = M * DIMC * 2;              // fp16 x / Q / K / Vt / O buffers
  const size_t WB = (size_t)DIMC * DIMC * 2;

  char* w = (char*)d_ws;
  u16* xb   = (u16*)w; w += XB;
  u16* Wqb  = (u16*)w; w += WB;
  u16* Wkb  = (u16*)w; w += WB;
  u16* Wvb  = (u16*)w; w += WB;
  u16* Wpb  = (u16*)w; w += WB;
  u16* Qb   = (u16*)w; w += XB;
  u16* Kbuf = (u16*)w; w += XB;
  u16* Vtb  = (u16*)w; w += XB;
  u16* Obuf = (u16*)w; w += XB;

  cast_f32_to_f16<<<6144, 256, 0, stream>>>(x,  xb,  (int)(M * DIMC / 4));
  cast_f32_to_f16<<<576,  256, 0, stream>>>(Wq, Wqb, (int)(WB / 8));
  cast_f32_to_f16<<<576,  256, 0, stream>>>(Wk, Wkb, (int)(WB / 8));
  cast_f32_to_f16<<<576,  256, 0, stream>>>(Wv, Wvb, (int)(WB / 8));
  cast_f32_to_f16<<<576,  256, 0, stream>>>(Wp, Wpb, (int)(WB / 8));

  dim3 gg(64, 6);
  gemm_nt<0><<<gg, 256, 0, stream>>>(xb, Wqb, 0.125f, nullptr, Qb);    // Q pre-scaled
  gemm_nt<0><<<gg, 256, 0, stream>>>(xb, Wkb, 1.0f,   nullptr, Kbuf);
  gemm_nt<1><<<gg, 256, 0, stream>>>(xb, Wvb, 1.0f,   nullptr, Vtb);   // V transposed

  attn_kernel<<<dim3(256, NHEADS, 2), 1024, 0, stream>>>(Qb, Kbuf, Vtb, Obuf);

  gemm_nt<2><<<gg, 256, 0, stream>>>(Obuf, Wpb, 1.0f, bp, out);
}

// Round 5
// 1281.949 us; speedup vs baseline: 1.9960x; 1.3040x over previous
//
#include <hip/hip_runtime.h>

// SparseFinerAttention on MI355X — round 5 (select-phase VALU diet: exp-keys + SWAR counting)
// B=2 N=4096 C=768 H=12 D=64 SCALE=1/8 K_keep=409
//
// Pipeline: cast->fp16; Q/K/V NT-GEMMs (MFMA 16x16x32_f16); fused attention
// (QK^T -> exp in f32 -> exact top-k on positive fp16 exp-keys -> masked PV,
//  invZ deferred to epilogue); out GEMM+bias.

typedef unsigned short u16;
typedef unsigned int   u32;
typedef float    f32x4 __attribute__((ext_vector_type(4)));
typedef _Float16 f16x8 __attribute__((ext_vector_type(8)));
typedef u16      u16x8 __attribute__((ext_vector_type(8)));
typedef u16      u16x4 __attribute__((ext_vector_type(4)));
typedef u32      u32x4 __attribute__((ext_vector_type(4)));

#define NHEADS 12
#define SEQ    4096
#define DIMC   768
#define HDIM   64
#define KKEEP  409

__device__ __forceinline__ f32x4 mfma16(f16x8 a, f16x8 b, f32x4 c) {
  return __builtin_amdgcn_mfma_f32_16x16x32_f16(a, b, c, 0, 0, 0);
}
__device__ __forceinline__ u16 f2h_bits(float f) {
  return __builtin_bit_cast(u16, (_Float16)f);
}

// ---------------- cast fp32 -> fp16 (vectorized) ----------------
__global__ __launch_bounds__(256) void cast_f32_to_f16(const float* __restrict__ in,
                                                       u16* __restrict__ out, int n4) {
  int i = blockIdx.x * 256 + threadIdx.x;
  if (i >= n4) return;
  float4 v = ((const float4*)in)[i];
  u16x4 o;
  o[0] = f2h_bits(v.x); o[1] = f2h_bits(v.y); o[2] = f2h_bits(v.z); o[3] = f2h_bits(v.w);
  ((u16x4*)out)[i] = o;
}

// ---------------- NT GEMM: C[M][768] = A[M][768] @ B[768][768]^T ----------------
// MODE 0: store fp16, head layout dst[b][h][n][d], value*scale   (Q with scale=0.125, K scale=1)
// MODE 1: store fp16, transposed head layout dst[b][h][d][n]     (V)
// MODE 2: store fp32 + bias, flat [M][768]                       (final projection)
template<int MODE>
__global__ __launch_bounds__(256) void gemm_nt(const u16* __restrict__ A, const u16* __restrict__ B,
                                               float scale, const float* __restrict__ bias,
                                               void* __restrict__ dstv) {
  __shared__ __align__(16) u16 As[128 * 64];
  __shared__ __align__(16) u16 Bs[128 * 64];
  const int tid  = threadIdx.x;
  const int lane = tid & 63, wave = tid >> 6;
  const int l15 = lane & 15, l4 = lane >> 4;
  const int row0 = blockIdx.x * 128, col0 = blockIdx.y * 128;
  const int wr = (wave >> 1) * 64, wc = (wave & 1) * 64;
  f32x4 acc[4][4];
#pragma unroll
  for (int i = 0; i < 4; i++)
#pragma unroll
    for (int j = 0; j < 4; j++) acc[i][j] = f32x4{0.f, 0.f, 0.f, 0.f};

  for (int k0 = 0; k0 < DIMC; k0 += 64) {
#pragma unroll
    for (int i = 0; i < 4; i++) {
      int id = tid + i * 256;
      int r = id >> 3, c = id & 7;
      f16x8 va = *(const f16x8*)(A + (size_t)(row0 + r) * DIMC + k0 + c * 8);
      f16x8 vb = *(const f16x8*)(B + (size_t)(col0 + r) * DIMC + k0 + c * 8);
      *(f16x8*)(As + r * 64 + ((c ^ (r & 7)) << 3)) = va;
      *(f16x8*)(Bs + r * 64 + ((c ^ (r & 7)) << 3)) = vb;
    }
    __syncthreads();
#pragma unroll
    for (int ks = 0; ks < 2; ++ks) {
      f16x8 af[4], bfr[4];
#pragma unroll
      for (int i = 0; i < 4; i++) {
        int r = wr + i * 16 + l15;
        int c = ks * 4 + l4;
        af[i] = *(const f16x8*)(As + r * 64 + ((c ^ (r & 7)) << 3));
        int r2 = wc + i * 16 + l15;
        bfr[i] = *(const f16x8*)(Bs + r2 * 64 + ((c ^ (r2 & 7)) << 3));
      }
#pragma unroll
      for (int i = 0; i < 4; i++)
#pragma unroll
        for (int j = 0; j < 4; j++) acc[i][j] = mfma16(af[i], bfr[j], acc[i][j]);
    }
    __syncthreads();
  }

  // epilogue: C/D layout col=lane&15, row=(lane>>4)*4+jj  [m89-verified]
#pragma unroll
  for (int i = 0; i < 4; i++) {
#pragma unroll
    for (int j = 0; j < 4; j++) {
      int rowb = row0 + wr + i * 16 + (l4 << 2);
      int col  = col0 + wc + j * 16 + l15;
      if (MODE == 2) {
        float* dst = (float*)dstv;
        float bv = bias[col];
#pragma unroll
        for (int jj = 0; jj < 4; jj++)
          dst[(size_t)(rowb + jj) * DIMC + col] = acc[i][j][jj] + bv;
      } else if (MODE == 0) {
        u16* dst = (u16*)dstv;
        int hh = col >> 6, d = col & 63;
#pragma unroll
        for (int jj = 0; jj < 4; jj++) {
          int row = rowb + jj;
          int bb = row >> 12, n = row & 4095;
          dst[(((size_t)bb * NHEADS + hh) * SEQ + n) * HDIM + d] = f2h_bits(acc[i][j][jj] * scale);
        }
      } else { // MODE 1: V transposed [b][h][d][n]
        u16* dst = (u16*)dstv;
        int hh = col >> 6, d = col & 63;
        int bb = rowb >> 12, nb = rowb & 4095;
        u16x4 pack;
#pragma unroll
        for (int jj = 0; jj < 4; jj++) pack[jj] = f2h_bits(acc[i][j][jj] * scale);
        *(u16x4*)(dst + (((size_t)bb * NHEADS + hh) * HDIM + d) * SEQ + nb) = pack;
      }
    }
  }
}

// ---------------- fused attention ----------------
// 1 workgroup (1024 thr, 16 waves) per (b, h, 16-row q block).
// QK^T:  wave w keys [w*256,(w+1)*256) via swapped mfma(K,Q); stores fp16(exp(logit))
//        (monotone -> same top-k), accumulates per-row Z partials in f32.
// top-k: wave w owns row w; keys = positive fp16 bits (order-preserving as u16).
//        Packed pairs pre-OR'd with 0x80008000; SWAR count: (X-(m+1)*0x10001)&H.
//        15-iter binary search on [0,0x7FFF]; count(>t) tracked in-loop.
// PV:    wave w covers its 256 keys on unnormalized P̃; invZ applied in epilogue.
// S: [16][4096] fp16, XOR-swizzled: sidx(q,m) = q*4096 + (((m>>3) ^ (q&7))<<3 | (m&7))
__global__ __launch_bounds__(1024, 4) void attn_kernel(const u16* __restrict__ Q, const u16* __restrict__ Kb,
                                                       const u16* __restrict__ Vt, u16* __restrict__ Ob) {
  __shared__ __align__(16) u16 S[16 * 4096];      // 128 KB (re-used for fp32 O-partials)
  __shared__ float zbuf[16][64];                  // per-row Z partials [row][wave*4+l4]
  __shared__ float invZs[16];
  const int tid  = threadIdx.x;
  const int lane = tid & 63, wave = tid >> 6;
  const int l15 = lane & 15, l4 = lane >> 4;
  const int h = blockIdx.y, b = blockIdx.z;
  const int bh = b * NHEADS + h;
  const int q0 = blockIdx.x * 16;
  const u16* Qh = Q  + ((size_t)bh * SEQ + q0) * HDIM;
  const u16* Kh = Kb + (size_t)bh * SEQ * HDIM;
  const u16* Vh = Vt + (size_t)bh * HDIM * SEQ;

  // Q fragments (rows q0..q0+15), Q already pre-scaled by 1/8. B-operand: l15 = q row.
  f16x8 qa0 = *(const f16x8*)(Qh + l15 * HDIM + l4 * 8);
  f16x8 qa1 = *(const f16x8*)(Qh + l15 * HDIM + 32 + l4 * 8);

  // ---- QK^T (swapped) + exp + Z partial: wave w covers keys [w*256, (w+1)*256) ----
  const int m0base = wave * 256;
  float zp = 0.f;                                 // partial Z for row l15
  {
    const u16* kptr = Kh + (size_t)(m0base + l15) * HDIM + l4 * 8;
    f16x8 kb0 = *(const f16x8*)kptr;
    f16x8 kb1 = *(const f16x8*)(kptr + 32);
#pragma unroll 1
    for (int t = 0; t < 16; ++t) {
      f16x8 cur0 = kb0, cur1 = kb1;
      if (t < 15) {
        const u16* kpn = Kh + (size_t)(m0base + (t + 1) * 16 + l15) * HDIM + l4 * 8;
        kb0 = *(const f16x8*)kpn;
        kb1 = *(const f16x8*)(kpn + 32);
      }
      f32x4 acc = f32x4{0.f, 0.f, 0.f, 0.f};
      acc = mfma16(cur0, qa0, acc);
      acc = mfma16(cur1, qa1, acc);
      int m0 = m0base + t * 16;
      int g = (m0 >> 3) + (l4 >> 1);              // 8-key group index
      u16x4 pack;
#pragma unroll
      for (int j = 0; j < 4; j++) {
        float e = __expf(fminf(acc[j], 11.0f));   // clamp keeps fp16 finite
        zp += e;
        pack[j] = f2h_bits(e);
      }
      *(u16x4*)(S + (l15 << 12) + ((g ^ (l15 & 7)) << 3) + ((l4 & 1) << 2)) = pack;
    }
  }
  zbuf[l15][(wave << 2) + l4] = zp;
  __syncthreads();

  // ---- exact top-k(409) per row; wave w owns row w ----
  {
    const u32 rbase = (u32)wave << 12;
    const u32 rx = (u32)(wave & 7) << 3;
    const u32 H = 0x80008000u;
    // cache row as packed key-pairs, pre-OR'd with H (keys positive fp16 -> <0x8000)
    u32 X[8][4];
#pragma unroll
    for (int cc = 0; cc < 8; ++cc) {
      u32 c = (u32)cc * 64 + lane;
      u32x4 v = *(const u32x4*)(S + rbase + ((c << 3) ^ rx));
#pragma unroll
      for (int p = 0; p < 4; p++) X[cc][p] = v[p] | H;
    }
    // binary search on [0,0x7FFF]: t = smallest v with count(key > v) < KKEEP
    u32 lo = 0, hi = 0x7FFFu, c1 = 0;
    while (lo < hi) {
      u32 mid = (lo + hi) >> 1;
      u32 M1 = (mid + 1) * 0x10001u;
      u32 pc = 0;                                  // packed per-half counts
#pragma unroll
      for (int cc = 0; cc < 8; ++cc)
#pragma unroll
        for (int p = 0; p < 4; p++) {
          u32 d = X[cc][p] - M1;                   // per-half: bit15 set iff half > mid
          pc += (d & H) >> 15;
        }
#pragma unroll
      for (int o = 32; o; o >>= 1) pc += __shfl_xor(pc, o);
      u32 cnt = (pc & 0xFFFFu) + (pc >> 16);
      if (cnt < KKEEP) { hi = mid; c1 = cnt; } else lo = mid + 1;
    }
    const u32 t = lo;
    // Z reduce (partials from QK^T phase)
    float z = zbuf[wave][lane];
#pragma unroll
    for (int o = 32; o; o >>= 1) z += __shfl_xor(z, o);
    if (lane == 0) invZs[wave] = 1.f / z;
    const int r = KKEEP - (int)c1;                 // ==t entries kept (lowest index first)

    // write-back masked (unnormalized) weights
    const u32 M1t = (t + 1) * 0x10001u;
    const u32 M0t = t * 0x10001u;
    int run = 0;                                   // ==t count in preceding chunks (row-wide)
#pragma unroll 1
    for (int cc = 0; cc < 8; ++cc) {
      u32 g1[4], eqm[4], eqany = 0;
#pragma unroll
      for (int p = 0; p < 4; p++) {
        u32 x = X[cc][p];
        g1[p] = (x - M1t) & H;                     // > t
        u32 g0 = (x - M0t) & H;                    // >= t  (t=0: x&H = H, all set)
        eqm[p] = g0 ^ g1[p];                       // == t
        eqany |= eqm[p];
      }
      u32 c = (u32)cc * 64 + lane;
      u32* dst = (u32*)(S + rbase + ((c << 3) ^ rx));
      if (!__any(eqany != 0)) {                    // tie-free chunk (common): branchless masks
        u32x4 o;
#pragma unroll
        for (int p = 0; p < 4; p++) {
          u32 m = g1[p] | (g1[p] - (g1[p] >> 15)); // 0x8000-bit -> 0xFFFF per kept half
          o[p] = X[cc][p] & m & 0x7FFF7FFFu;
        }
        *(u32x4*)dst = o;
      } else {                                     // rare: exact tie ranking
        u32 s = 0;
#pragma unroll
        for (int p = 0; p < 4; p++) s += eqm[p] >> 15;   // bits at 0 and 16
        int ec = (int)((s & 0xFFFFu) + (s >> 16));
        int inc = ec;
#pragma unroll
        for (int o = 1; o < 64; o <<= 1) { int pfx = __shfl_up(inc, o); if (lane >= o) inc += pfx; }
        int rk = run + inc - ec;
        run += __shfl(inc, 63);
        u32x4 o;
#pragma unroll
        for (int p = 0; p < 4; p++) {
          u32 x = X[cc][p];
          u32 glo = (g1[p] >> 15) & 1u, ghi = g1[p] >> 31;
          u32 elo = (eqm[p] >> 15) & 1u, ehi = eqm[p] >> 31;
          u32 klo = glo | (elo & (rk < r ? 1u : 0u)); rk += (int)elo;
          u32 khi = ghi | (ehi & (rk < r ? 1u : 0u)); rk += (int)ehi;
          o[p] = x & ((klo ? 0xFFFFu : 0u) | (khi ? 0xFFFF0000u : 0u)) & 0x7FFF7FFFu;
        }
        *(u32x4*)dst = o;
      }
    }
  }
  __syncthreads();

  // ---- masked dense PV on unnormalized P̃; wave w covers its 256 keys ----
  f32x4 oacc[4];
#pragma unroll
  for (int dt = 0; dt < 4; dt++) oacc[dt] = f32x4{0.f, 0.f, 0.f, 0.f};
#pragma unroll 1
  for (int ks = 0; ks < 8; ++ks) {
    int mb = wave * 256 + ks * 32;
    u32 c = (u32)(mb >> 3) + l4;
    f16x8 pa = *(const f16x8*)(S + (l15 << 12) + (((c ^ (l15 & 7))) << 3));
#pragma unroll
    for (int dt = 0; dt < 4; ++dt) {
      const u16* vp = Vh + (size_t)(dt * 16 + l15) * SEQ + mb + l4 * 8;
      f16x8 vb = *(const f16x8*)vp;
      oacc[dt] = mfma16(pa, vb, oacc[dt]);
    }
  }
  __syncthreads();                 // P fully consumed -> S reusable for fp32 partials
  float* Op = (float*)S;           // [16 waves][16 rows][stride 65] fp32 = 66.5 KB
#pragma unroll
  for (int dt = 0; dt < 4; dt++)
#pragma unroll
    for (int j = 0; j < 4; j++)
      Op[(wave * 16 + l4 * 4 + j) * 65 + dt * 16 + l15] = oacc[dt][j];
  __syncthreads();
  {
    int row = tid >> 6, d = tid & 63;   // exactly 1024 outputs
    float v = 0.f;
#pragma unroll
    for (int w = 0; w < 16; ++w) v += Op[(w * 16 + row) * 65 + d];
    v *= invZs[row];                    // deferred softmax normalization
    Ob[((size_t)b * SEQ + q0 + row) * DIMC + h * HDIM + d] = f2h_bits(v);
  }
}

// ---------------- launch ----------------
extern "C" void kernel_launch(void* const* d_in, const int* in_sizes, int n_in,
                              void* d_out, int out_size, void* d_ws, size_t ws_size,
                              hipStream_t stream) {
  const float* x  = (const float*)d_in[0];
  const float* Wq = (const float*)d_in[1];
  const float* Wk = (const float*)d_in[2];
  const float* Wv = (const float*)d_in[3];
  const float* Wp = (const float*)d_in[4];
  const float* bp = (const float*)d_in[5];
  float* out = (float*)d_out;

  const size_t M = 2 * (size_t)SEQ;            // 8192
  const size_t XB = M * DIMC * 2;              // fp16 x / Q / K / Vt / O buffers
  const size_t WB = (size_t)DIMC * DIMC * 2;

  char* w = (char*)d_ws;
  u16* xb   = (u16*)w; w += XB;
  u16* Wqb  = (u16*)w; w += WB;
  u16* Wkb  = (u16*)w; w += WB;
  u16* Wvb  = (u16*)w; w += WB;
  u16* Wpb  = (u16*)w; w += WB;
  u16* Qb   = (u16*)w; w += XB;
  u16* Kbuf = (u16*)w; w += XB;
  u16* Vtb  = (u16*)w; w += XB;
  u16* Obuf = (u16*)w; w += XB;

  cast_f32_to_f16<<<6144, 256, 0, stream>>>(x,  xb,  (int)(M * DIMC / 4));
  cast_f32_to_f16<<<576,  256, 0, stream>>>(Wq, Wqb, (int)(WB / 8));
  cast_f32_to_f16<<<576,  256, 0, stream>>>(Wk, Wkb, (int)(WB / 8));
  cast_f32_to_f16<<<576,  256, 0, stream>>>(Wv, Wvb, (int)(WB / 8));
  cast_f32_to_f16<<<576,  256, 0, stream>>>(Wp, Wpb, (int)(WB / 8));

  dim3 gg(64, 6);
  gemm_nt<0><<<gg, 256, 0, stream>>>(xb, Wqb, 0.125f, nullptr, Qb);    // Q pre-scaled
  gemm_nt<0><<<gg, 256, 0, stream>>>(xb, Wkb, 1.0f,   nullptr, Kbuf);
  gemm_nt<1><<<gg, 256, 0, stream>>>(xb, Wvb, 1.0f,   nullptr, Vtb);   // V transposed

  attn_kernel<<<dim3(256, NHEADS, 2), 1024, 0, stream>>>(Qb, Kbuf, Vtb, Obuf);

  gemm_nt<2><<<gg, 256, 0, stream>>>(Obuf, Wpb, 1.0f, bp, out);
}